// Round 10
// baseline (78.475 us; speedup 1.0000x reference)
//
#include <hip/hip_runtime.h>
#include <hip/hip_bf16.h>

// DiffAlphaSplitModel: VOCAB=64, H=64, HALF=32, B=256, L=2048.
//  DUAL-SPACE per-position recurrence (no chunk solve):
//    gf_v = k_v . u  (lane = vocab v, 64-wide);  backward over positions:
//      d = gf[t_p] (v_readlane, SGPR token)      [chain]
//      gf -= d * (c_p * G[:,t_p])                [chain: ONE v_fmac]
//      W[t_p] += c_p * d                         [off-chain vocab histogram]
//    r = sum_v W_v h_v  at the end.  EXACT reference order.
//  ROUND-10 CHANGES (vs r9's 83 cy/pos):
//   a) tokens go through __builtin_amdgcn_readfirstlane in the BATCH phase ->
//      true SGPRs; kills the per-position readfirstlane + lane-select hazard
//      that sat on the serial chain.
//   b) G-columns prescaled by c_j in the batch (cgp), so the chain is only
//      readlane -> fmac.
//   c) block-level software pipeline: BATCH(k+1); sched_barrier(0); CHAIN(k)
//      with two small named banks (tokens in SGPR, cgp in VGPR). Batch has
//      ZERO dependence on gf -> no correction terms (unlike r6/r8 attempts).
//  s-chain and e-chain in separate waves (block=128).
//
// ws layout (floats):
//   [0     ..  4095] compact k [2][64][32]
//   [4096  ..  8191] compact h [2][64][32]
//   [16384 .. 24575] Gram [2][64][64]
//   [24576 .. 40959] rbuf [256][64]

#define L_SEQ 2048
#define NPOS  2047

__device__ __forceinline__ float rdlane(float v, int l) {
    return __int_as_float(__builtin_amdgcn_readlane(__float_as_int(v), l));
}

// ---------------- Kernel A: per-vocab tables -------------------------------
__global__ void build_tables(const float* __restrict__ embed,
                             const float* __restrict__ w1, const float* __restrict__ b1,
                             const float* __restrict__ w2, const float* __restrict__ b2,
                             const float* __restrict__ ln_g, const float* __restrict__ ln_b,
                             const float* __restrict__ ws, const float* __restrict__ bs,
                             const float* __restrict__ we, const float* __restrict__ be,
                             float* __restrict__ tabs) {
    const int v = blockIdx.x;
    const int t = threadIdx.x;        // 0..63
    __shared__ float sh_h[64];
    __shared__ float sh_a[128];
    __shared__ float sh_x[64];

    sh_h[t] = embed[v * 64 + t];
    __syncthreads();

    float acc0 = b1[t], acc1 = b1[t + 64];
    #pragma unroll 8
    for (int k = 0; k < 64; ++k) {
        const float hv = sh_h[k];
        acc0 += hv * w1[k * 128 + t];
        acc1 += hv * w1[k * 128 + t + 64];
    }
    sh_a[t]      = fmaxf(acc0, 0.f);
    sh_a[t + 64] = fmaxf(acc1, 0.f);
    __syncthreads();

    float x = sh_h[t] + b2[t];
    #pragma unroll 8
    for (int k = 0; k < 128; ++k) x += sh_a[k] * w2[k * 64 + t];

    float mu = x;
    for (int m = 1; m <= 32; m <<= 1) mu += __shfl_xor(mu, m);
    mu *= (1.f / 64.f);
    const float dx = x - mu;
    float var = dx * dx;
    for (int m = 1; m <= 32; m <<= 1) var += __shfl_xor(var, m);
    var *= (1.f / 64.f);
    const float hln = dx * rsqrtf(var + 1e-5f) * ln_g[t] + ln_b[t];
    sh_x[t] = hln;
    __syncthreads();

    const int j   = t & 31;
    const int mem = t >> 5;
    const float* W  = mem ? we : ws;
    const float* Bv = mem ? be : bs;
    float p = Bv[j];
    #pragma unroll 8
    for (int k = 0; k < 64; ++k) p += sh_x[k] * W[k * 32 + j];

    float nn = p * p;
    for (int m = 1; m <= 16; m <<= 1) nn += __shfl_xor(nn, m);
    const float kn = p / fmaxf(sqrtf(nn), 1e-12f);

    tabs[(mem * 64 + v) * 32 + j]        = kn;   // normalized key
    tabs[4096 + (mem * 64 + v) * 32 + j] = p;    // raw projection
}

// ---------------- Kernel A2: Gram tables -----------------------------------
__global__ void gram_kernel(const float* __restrict__ tabs, float* __restrict__ gout) {
    const int v  = blockIdx.x;
    const int tt = threadIdx.x;          // 0..127
    const int m  = tt >> 6, w = tt & 63;
    __shared__ float kv[64];
    if (tt < 64) kv[tt] = tabs[((tt >> 5) * 64 + v) * 32 + (tt & 31)];
    __syncthreads();
    const float* kw  = &tabs[(m * 64 + w) * 32];
    const float* kvm = &kv[m * 32];
    float acc = 0.f;
    #pragma unroll 8
    for (int j = 0; j < 32; ++j) acc += kvm[j] * kw[j];
    gout[m * 4096 + v * 64 + w] = acc;
}

// ======== batch / chain macros (static indexing, named banks) ===============
// BATCH: tokens (SGPR via readfirstlane) + prescaled G-columns for block at PB.
#define BATCH(PB, TK, CGP, CB)                                                \
  do {                                                                        \
    const int pb_ = (PB);                                                     \
    _Pragma("unroll")                                                         \
    for (int j = 0; j < 32; ++j)                                              \
      TK[j] = __builtin_amdgcn_readfirstlane(srow[pb_ + j]);                  \
    CB = mF ? (float)(pb_ + 1) * invL : 1.0f;                                 \
    _Pragma("unroll")                                                         \
    for (int j = 0; j < 32; ++j) {                                            \
      const float g_ = gt[rowV + TK[j]];                                      \
      const float c_ = CB + (float)j * invLe;                                 \
      CGP[j] = c_ * g_;                                                       \
    }                                                                         \
  } while (0)

// CHAIN: 32 backward positions. Chain = readlane -> fmac; W-hist off-chain.
#define CHAIN(TK, CGP, CB)                                                    \
  do {                                                                        \
    _Pragma("unroll")                                                         \
    for (int j = 31; j >= 0; --j) {                                           \
      const float d_ = rdlane(gf, TK[j]);                                     \
      gf = fmaf(-d_, CGP[j], gf);                                             \
      const float c_ = CB + (float)j * invLe;                                 \
      const float e_ = c_ * d_;                                               \
      W += (lane == TK[j]) ? e_ : 0.f;                                        \
    }                                                                         \
  } while (0)

// ---------------- Kernel B: per-position dual-space scan (pipelined) -------
// grid 256 (batch), block 128 = 2 waves. wave 0: s-chain (c=1), wave 1: e-chain.
// lane (0..63) = vocab id v for gf / W.
// Blocks k=0..63 cover positions pb_k = 2016-32k .. pb_k+31; position 2047
// in block k=0 is neutralized with c=0 (e=0, cgp=0).
__global__ void __launch_bounds__(128, 1) scan_kernel(const int* __restrict__ seq,
                                                      const float* __restrict__ tabs,
                                                      float* __restrict__ rbuf) {
    const int b    = blockIdx.x;
    const int tid  = threadIdx.x;        // 0..127
    const int m    = tid >> 6;           // wave id == chain id
    const int lane = tid & 63;           // vocab id v
    const int q    = lane & 31;

    __shared__ float gt [2 * 64 * 65];   // Gram rows padded to 65
    __shared__ float hsh[2 * 64 * 32];   // h tables [m][v][j]

    // ---- stage (one-time) ----
    for (int i = tid; i < 8192; i += 128) {
        const int mm = i >> 12, v = (i >> 6) & 63, ww = i & 63;
        gt[mm * 4160 + v * 65 + ww] = tabs[16384 + i];
    }
    for (int i = tid; i < 1024; i += 128)
        ((float4*)hsh)[i] = ((const float4*)(tabs + 4096))[i];
    __syncthreads();

    const int*  srow  = seq + b * L_SEQ;        // uniform base -> s_load
    const int   rowV  = m * 4160 + lane * 65;   // per-lane G row base
    const float invL  = 1.0f / (float)L_SEQ;
    const bool  mF    = (m != 0);
    const float invLe = mF ? invL : 0.0f;       // c step (0 for s-chain)

    // init: u = k_tokL  =>  gf_v = G[v][tokL]
    const int tokL = __builtin_amdgcn_readfirstlane(srow[NPOS]);
    float gf = gt[rowV + tokL];
    float W  = 0.f;

    int   tkA[32], tkB[32];
    float cgpA[32], cgpB[32];
    float cbA, cbB;

    // prologue: batch block k=0 (pb=2016), neutralize position 2047 (j=31)
    BATCH(2016, tkA, cgpA, cbA);
    cgpA[31] = 0.f;
    // note: CHAIN computes e with c = cb + 31*invLe != 0, but d*... we zero it
    // via cgp only for gf; for W we must also kill e at j=31 of block 0.
    // Simplest exact fix: make token at j=31 harmless by relying on e_*cgp for
    // gf (zeroed) and subtracting its W contribution is NOT possible -> use a
    // dedicated first chain below instead.

    // ---- first chain (block k=0) with explicit j=31 skip ----
    {
        __builtin_amdgcn_sched_barrier(0);
        #pragma unroll
        for (int j = 30; j >= 0; --j) {
            const float d_ = rdlane(gf, tkA[j]);
            gf = fmaf(-d_, cgpA[j], gf);
            const float c_ = cbA + (float)j * invLe;
            const float e_ = c_ * d_;
            W += (lane == tkA[j]) ? e_ : 0.f;
        }
    }

    // ---- main pipelined loop: blocks k=1..63 (pb = 1984 down to 0) ----
    // 31 iterations x 2 blocks: k=2i+1 (B), k=2i+2 (A); batches one ahead.
    BATCH(1984, tkB, cgpB, cbB);
    for (int i = 0; i < 31; ++i) {
        if (__all(fabsf(gf) < 1e-6f)) break;   // residual-based exit (per wave)
        const int pbA = 1952 - 64 * i;         // k = 2i+2
        BATCH(pbA, tkA, cgpA, cbA);
        __builtin_amdgcn_sched_barrier(0);
        CHAIN(tkB, cgpB, cbB);                 // k = 2i+1
        const int pbB = pbA - 32;              // k = 2i+3 (clamped at last)
        const int pbBc = (pbB >= 0) ? pbB : 0;
        BATCH(pbBc, tkB, cgpB, cbB);
        __builtin_amdgcn_sched_barrier(0);
        CHAIN(tkA, cgpA, cbA);                 // k = 2i+2
    }
    // epilogue: block k=63 (pb=0) sits in bank B after the last iteration
    if (!__all(fabsf(gf) < 1e-6f)) {
        __builtin_amdgcn_sched_barrier(0);
        CHAIN(tkB, cgpB, cbB);
    }

    // ---- final: r_q = sum_v W_v * h[v][q] ----
    float r = 0.f;
    #pragma unroll 8
    for (int v = 0; v < 64; ++v) {
        const float wv = rdlane(W, v);
        r = fmaf(wv, hsh[(m * 64 + v) * 32 + q], r);
    }

    if (lane < 32)
        rbuf[b * 64 + m * 32 + q] = r;   // [rs | re] = concat order
}

// ---------------- Kernel C: output projection ------------------------------
__global__ void out_kernel(const float* __restrict__ rbuf,
                           const float* __restrict__ wrp, const float* __restrict__ brp,
                           const float* __restrict__ wout, const float* __restrict__ bout,
                           float* __restrict__ out) {
    const int b = blockIdx.x;
    const int t = threadIdx.x;
    __shared__ float rsh[64];
    __shared__ float ysh[64];

    rsh[t] = rbuf[b * 64 + t];
    __syncthreads();

    float y = brp[t];
    #pragma unroll 8
    for (int k = 0; k < 64; ++k) y += rsh[k] * wrp[k * 64 + t];
    ysh[t] = y;
    __syncthreads();

    float o = bout[t];
    #pragma unroll 8
    for (int k = 0; k < 64; ++k) o += ysh[k] * wout[k * 64 + t];
    out[b * 64 + t] = o;
}

// ---------------- launch ----------------------------------------------------
extern "C" void kernel_launch(void* const* d_in, const int* in_sizes, int n_in,
                              void* d_out, int out_size, void* d_ws, size_t ws_size,
                              hipStream_t stream) {
    const int*   seq   = (const int*)  d_in[0];
    const float* embed = (const float*)d_in[1];
    const float* w1    = (const float*)d_in[2];
    const float* b1    = (const float*)d_in[3];
    const float* w2    = (const float*)d_in[4];
    const float* b2    = (const float*)d_in[5];
    const float* ln_g  = (const float*)d_in[6];
    const float* ln_b  = (const float*)d_in[7];
    const float* ws    = (const float*)d_in[8];
    const float* bs    = (const float*)d_in[9];
    const float* we    = (const float*)d_in[10];
    const float* be    = (const float*)d_in[11];
    const float* wrp   = (const float*)d_in[12];
    const float* brp   = (const float*)d_in[13];
    const float* wout  = (const float*)d_in[14];
    const float* bout  = (const float*)d_in[15];

    float* tabs = (float*)d_ws;              // tables + gram
    float* gout = tabs + 16384;              // gram [2][64][64]
    float* rbuf = tabs + 24576;              // r vectors [256][64]

    build_tables<<<64, 64, 0, stream>>>(embed, w1, b1, w2, b2, ln_g, ln_b,
                                        ws, bs, we, be, tabs);
    gram_kernel<<<64, 128, 0, stream>>>(tabs, gout);
    scan_kernel<<<256, 128, 0, stream>>>(seq, tabs, rbuf);
    out_kernel<<<256, 64, 0, stream>>>(rbuf, wrp, brp, wout, bout, (float*)d_out);
}